// Round 1
// baseline (1533.757 us; speedup 1.0000x reference)
//
#include <hip/hip_runtime.h>

// ---------------------------------------------------------------------------
// Problem constants (fixed by setup_inputs)
// ---------------------------------------------------------------------------
#define N_OP   50000
#define N_M    5000
#define N_A    2000
#define C_OP   256
#define C_M    128
#define C_A    128
#define E_OO   200000
#define E_OM   200000
#define E_MA   60000
#define E_DIM  8

#define OUT_OP_OFF 0
#define OUT_M_OFF  (N_OP * C_OP)                 // 12,800,000
#define OUT_A_OFF  (N_OP * C_OP + N_M * C_M)     // 13,440,000

// ---------------------------------------------------------------------------
// GEMM: out[M][N] = A[M][K] @ W[K][N] (+ bias[N]).  One block computes TM rows
// of all N columns.  A rows staged in LDS (broadcast reads), W is L2-resident.
// blockDim.x == N (128 or 256).  Requires M % TM == 0.
// ---------------------------------------------------------------------------
template <int K, int N, int TM, bool HAS_BIAS>
__global__ void gemm_bias(const float* __restrict__ A, const float* __restrict__ W,
                          const float* __restrict__ bias, float* __restrict__ out) {
    __shared__ float As[TM][K];
    const int m0 = blockIdx.x * TM;
    const int tid = threadIdx.x;

    for (int idx = tid; idx < TM * K; idx += N) {
        int r = idx / K, k = idx - r * K;
        As[r][k] = A[(m0 + r) * K + k];
    }
    __syncthreads();

    float acc[TM];
    const float b = HAS_BIAS ? bias[tid] : 0.0f;
#pragma unroll
    for (int r = 0; r < TM; ++r) acc[r] = b;

    for (int k = 0; k < K; k += 4) {
#pragma unroll
        for (int kk = 0; kk < 4; ++kk) {
            const float w = W[(k + kk) * N + tid];
#pragma unroll
            for (int r = 0; r < TM; ++r) acc[r] += As[r][k + kk] * w;
        }
    }
#pragma unroll
    for (int r = 0; r < TM; ++r) out[(m0 + r) * N + tid] = acc[r];
}

// ---------------------------------------------------------------------------
// Per-node init: segment-max (order-preserving uint encoding) and denom.
// ---------------------------------------------------------------------------
__global__ void init_node(unsigned* __restrict__ nmax, float* __restrict__ denom, int n) {
    int i = blockIdx.x * blockDim.x + threadIdx.x;
    if (i < n) { nmax[i] = 0u; denom[i] = 0.0f; }
}

// out = x + b1 (+ b2): residual + per-conv output bias, pre-applied so the
// edge aggregation can atomicAdd straight into d_out.
template <int C>
__global__ void init_out(const float* __restrict__ x, const float* __restrict__ b1,
                         const float* __restrict__ b2, float* __restrict__ out, int total) {
    int i = blockIdx.x * blockDim.x + threadIdx.x;
    if (i < total) {
        int c = i & (C - 1);
        float v = x[i] + b1[c];
        if (b2) v += b2[c];
        out[i] = v;
    }
}

__device__ __forceinline__ unsigned enc_f32(float f) {
    unsigned u = __float_as_uint(f);
    return (u & 0x80000000u) ? ~u : (u | 0x80000000u);
}
__device__ __forceinline__ float dec_f32(unsigned u) {
    return (u & 0x80000000u) ? __uint_as_float(u ^ 0x80000000u) : __uint_as_float(~u);
}

// ---------------------------------------------------------------------------
// Edge logit: e = leaky_relu(xl[src] + xr[dst] (+ ef[edge])) . att
// One 64-lane wave per edge; shfl butterfly reduction; atomicMax for seg-max.
// ---------------------------------------------------------------------------
template <int C, bool HAS_EF>
__global__ void edge_logit(const float* __restrict__ xl, const float* __restrict__ xr,
                           const float* __restrict__ ef, const float* __restrict__ att,
                           const int* __restrict__ src, const int* __restrict__ dst,
                           float* __restrict__ e_out, unsigned* __restrict__ nmax, int E) {
    const int edge = blockIdx.x * (blockDim.x >> 6) + (threadIdx.x >> 6);
    if (edge >= E) return;
    const int lane = threadIdx.x & 63;
    const int s = src[edge], d = dst[edge];

    float acc = 0.0f;
#pragma unroll
    for (int i = 0; i < C / 64; ++i) {
        const int c = i * 64 + lane;
        float v = xl[s * C + c] + xr[d * C + c];
        if (HAS_EF) v += ef[edge * C + c];
        v = (v >= 0.0f) ? v : 0.2f * v;
        acc += v * att[c];
    }
#pragma unroll
    for (int o = 32; o > 0; o >>= 1) acc += __shfl_xor(acc, o, 64);

    if (lane == 0) {
        e_out[edge] = acc;
        atomicMax(&nmax[d], enc_f32(acc));
    }
}

// ---------------------------------------------------------------------------
// ee = exp(e - max[dst]); denom[dst] += ee
// ---------------------------------------------------------------------------
__global__ void edge_exp(float* __restrict__ e, const int* __restrict__ dst,
                         const unsigned* __restrict__ nmax, float* __restrict__ denom, int E) {
    int i = blockIdx.x * blockDim.x + threadIdx.x;
    if (i >= E) return;
    const int d = dst[i];
    const float m = dec_f32(nmax[d]);
    const float ee = __expf(e[i] - m);
    e[i] = ee;
    atomicAdd(&denom[d], ee);
}

// ---------------------------------------------------------------------------
// out[dst] += (ee/denom[dst]) * xl[src]   (one wave per edge, atomic scatter)
// ---------------------------------------------------------------------------
template <int C>
__global__ void edge_aggregate(const float* __restrict__ xl, const float* __restrict__ ee,
                               const float* __restrict__ denom,
                               const int* __restrict__ src, const int* __restrict__ dst,
                               float* __restrict__ out, int E) {
    const int edge = blockIdx.x * (blockDim.x >> 6) + (threadIdx.x >> 6);
    if (edge >= E) return;
    const int lane = threadIdx.x & 63;
    const int s = src[edge], d = dst[edge];
    const float alpha = ee[edge] / fmaxf(denom[d], 1e-16f);
#pragma unroll
    for (int i = 0; i < C / 64; ++i) {
        const int c = i * 64 + lane;
        atomicAdd(&out[d * C + c], alpha * xl[s * C + c]);
    }
}

// ---------------------------------------------------------------------------
// Launch
// ---------------------------------------------------------------------------
extern "C" void kernel_launch(void* const* d_in, const int* in_sizes, int n_in,
                              void* d_out, int out_size, void* d_ws, size_t ws_size,
                              hipStream_t stream) {
    const float* x_op    = (const float*)d_in[0];
    const float* x_m     = (const float*)d_in[1];
    const float* x_a     = (const float*)d_in[2];
    const int*   ei_pred = (const int*)d_in[3];   // [2][E_OO]: row0=src, row1=dst
    const int*   ei_succ = (const int*)d_in[4];
    const int*   src_o2m = (const int*)d_in[5];
    const int*   dst_o2m = (const int*)d_in[6];
    const int*   src_m2a = (const int*)d_in[7];
    const int*   dst_m2a = (const int*)d_in[8];
    const float* ea_m2a  = (const float*)d_in[9];

    const float* Wl_pred = (const float*)d_in[10];
    const float* bl_pred = (const float*)d_in[11];
    const float* Wr_pred = (const float*)d_in[12];
    const float* br_pred = (const float*)d_in[13];
    const float* att_pred= (const float*)d_in[14];
    const float* b_pred  = (const float*)d_in[15];

    const float* Wl_succ = (const float*)d_in[16];
    const float* bl_succ = (const float*)d_in[17];
    const float* Wr_succ = (const float*)d_in[18];
    const float* br_succ = (const float*)d_in[19];
    const float* att_succ= (const float*)d_in[20];
    const float* b_succ  = (const float*)d_in[21];

    const float* Wl_o2m  = (const float*)d_in[22];
    const float* bl_o2m  = (const float*)d_in[23];
    const float* Wr_o2m  = (const float*)d_in[24];
    const float* br_o2m  = (const float*)d_in[25];
    const float* att_o2m = (const float*)d_in[26];
    const float* b_o2m   = (const float*)d_in[27];

    const float* Wl_m2a  = (const float*)d_in[28];
    const float* bl_m2a  = (const float*)d_in[29];
    const float* Wr_m2a  = (const float*)d_in[30];
    const float* br_m2a  = (const float*)d_in[31];
    const float* att_m2a = (const float*)d_in[32];
    const float* b_m2a   = (const float*)d_in[33];
    const float* We_m2a  = (const float*)d_in[34];

    // workspace layout (floats)
    float* ws   = (float*)d_ws;
    float*    xl    = ws;                          // 12,800,000
    float*    xr    = ws + 12800000;               // 12,800,000
    float*    ebuf  = ws + 25600000;               // 200,000
    unsigned* nmax  = (unsigned*)(ws + 25800000);  // 50,000
    float*    denom = ws + 25850000;               // 50,000  -> total 103.6 MB

    float* out_op = (float*)d_out + OUT_OP_OFF;
    float* out_m  = (float*)d_out + OUT_M_OFF;
    float* out_a  = (float*)d_out + OUT_A_OFF;

    // ---- output init: residual + biases (aggregation atomicAdds on top) ----
    init_out<C_OP><<<(N_OP * C_OP + 255) / 256, 256, 0, stream>>>(x_op, b_pred, b_succ, out_op, N_OP * C_OP);
    init_out<C_M ><<<(N_M * C_M + 255) / 256, 256, 0, stream>>>(x_m, b_o2m, nullptr, out_m, N_M * C_M);
    init_out<C_A ><<<(N_A * C_A + 255) / 256, 256, 0, stream>>>(x_a, b_m2a, nullptr, out_a, N_A * C_A);

    // ---------------- conv 1: pred (op -> op, C=256) ----------------
    gemm_bias<256, 256, 4, true><<<N_OP / 4, 256, 0, stream>>>(x_op, Wl_pred, bl_pred, xl);
    gemm_bias<256, 256, 4, true><<<N_OP / 4, 256, 0, stream>>>(x_op, Wr_pred, br_pred, xr);
    init_node<<<(N_OP + 255) / 256, 256, 0, stream>>>(nmax, denom, N_OP);
    edge_logit<256, false><<<E_OO / 4, 256, 0, stream>>>(xl, xr, nullptr, att_pred,
                                                         ei_pred, ei_pred + E_OO, ebuf, nmax, E_OO);
    edge_exp<<<(E_OO + 255) / 256, 256, 0, stream>>>(ebuf, ei_pred + E_OO, nmax, denom, E_OO);
    edge_aggregate<256><<<E_OO / 4, 256, 0, stream>>>(xl, ebuf, denom,
                                                      ei_pred, ei_pred + E_OO, out_op, E_OO);

    // ---------------- conv 2: succ (op -> op, C=256) ----------------
    gemm_bias<256, 256, 4, true><<<N_OP / 4, 256, 0, stream>>>(x_op, Wl_succ, bl_succ, xl);
    gemm_bias<256, 256, 4, true><<<N_OP / 4, 256, 0, stream>>>(x_op, Wr_succ, br_succ, xr);
    init_node<<<(N_OP + 255) / 256, 256, 0, stream>>>(nmax, denom, N_OP);
    edge_logit<256, false><<<E_OO / 4, 256, 0, stream>>>(xl, xr, nullptr, att_succ,
                                                         ei_succ, ei_succ + E_OO, ebuf, nmax, E_OO);
    edge_exp<<<(E_OO + 255) / 256, 256, 0, stream>>>(ebuf, ei_succ + E_OO, nmax, denom, E_OO);
    edge_aggregate<256><<<E_OO / 4, 256, 0, stream>>>(xl, ebuf, denom,
                                                      ei_succ, ei_succ + E_OO, out_op, E_OO);

    // ---------------- conv 3: o2m (op -> machine, C=128) ----------------
    gemm_bias<256, 128, 4, true><<<N_OP / 4, 128, 0, stream>>>(x_op, Wl_o2m, bl_o2m, xl);
    gemm_bias<128, 128, 4, true><<<N_M / 4, 128, 0, stream>>>(x_m, Wr_o2m, br_o2m, xr);
    init_node<<<(N_M + 255) / 256, 256, 0, stream>>>(nmax, denom, N_M);
    edge_logit<128, false><<<E_OM / 4, 256, 0, stream>>>(xl, xr, nullptr, att_o2m,
                                                         src_o2m, dst_o2m, ebuf, nmax, E_OM);
    edge_exp<<<(E_OM + 255) / 256, 256, 0, stream>>>(ebuf, dst_o2m, nmax, denom, E_OM);
    edge_aggregate<128><<<E_OM / 4, 256, 0, stream>>>(xl, ebuf, denom,
                                                      src_o2m, dst_o2m, out_m, E_OM);

    // ---------------- conv 4: m2a (machine -> agv, C=128, edge feats) ----------------
    gemm_bias<128, 128, 4, true><<<N_M / 4, 128, 0, stream>>>(x_m, Wl_m2a, bl_m2a, xl);
    gemm_bias<128, 128, 4, true><<<N_A / 4, 128, 0, stream>>>(x_a, Wr_m2a, br_m2a, xr);
    float* ef = xr + N_A * C_A;  // 60000*128 fits well inside xr buffer
    gemm_bias<8, 128, 4, false><<<E_MA / 4, 128, 0, stream>>>(ea_m2a, We_m2a, nullptr, ef);
    init_node<<<(N_A + 255) / 256, 256, 0, stream>>>(nmax, denom, N_A);
    edge_logit<128, true><<<E_MA / 4, 256, 0, stream>>>(xl, xr, ef, att_m2a,
                                                        src_m2a, dst_m2a, ebuf, nmax, E_MA);
    edge_exp<<<(E_MA + 255) / 256, 256, 0, stream>>>(ebuf, dst_m2a, nmax, denom, E_MA);
    edge_aggregate<128><<<E_MA / 4, 256, 0, stream>>>(xl, ebuf, denom,
                                                      src_m2a, dst_m2a, out_a, E_MA);
}